// Round 13
// baseline (350.959 us; speedup 1.0000x reference)
//
#include <hip/hip_runtime.h>

typedef unsigned short u16;
typedef unsigned int u32;
typedef __bf16 bf16x4 __attribute__((ext_vector_type(4)));
typedef __bf16 bf16x8 __attribute__((ext_vector_type(8)));
typedef float f32x4 __attribute__((ext_vector_type(4)));
typedef float f32x16 __attribute__((ext_vector_type(16)));

#define BATCH 4
#define SLEN 2048
#define DMODEL 1024
#define NHEAD 16
#define DHEAD 64
#define MROWS (BATCH * SLEN) /* 8192 */

__device__ __forceinline__ u16 f32_to_bf16(float f) {
  u32 u = __float_as_uint(f);
  u32 r = (u + 0x7FFFu + ((u >> 16) & 1u)) >> 16;
  return (u16)r;
}
__device__ __forceinline__ u32 pack_bf16x2(float a, float b) {
  return (u32)f32_to_bf16(a) | ((u32)f32_to_bf16(b) << 16);
}

// pack two f32 -> two bf16 (truncate), 1 v_perm_b32
__device__ __forceinline__ u32 pack_trunc(float lo, float hi) {
#if __has_builtin(__builtin_amdgcn_perm)
  return __builtin_amdgcn_perm(__float_as_uint(hi), __float_as_uint(lo), 0x07060302u);
#else
  return (__float_as_uint(hi) & 0xFFFF0000u) | (__float_as_uint(lo) >> 16);
#endif
}
// pack with round-half-up (epilogue)
__device__ __forceinline__ u32 pack_round(float lo, float hi) {
  u32 ul = __float_as_uint(lo) + 0x8000u;
  u32 uh = __float_as_uint(hi) + 0x8000u;
#if __has_builtin(__builtin_amdgcn_perm)
  return __builtin_amdgcn_perm(uh, ul, 0x07060302u);
#else
  return (uh & 0xFFFF0000u) | (ul >> 16);
#endif
}

#if __has_builtin(__builtin_amdgcn_exp2f)
#define EXP2(x) __builtin_amdgcn_exp2f(x)
#else
#define EXP2(x) exp2f(x)
#endif

// async global->LDS, 16 B per lane; lds dest = wave-uniform base + lane*16
typedef const __attribute__((address_space(1))) void* gas_cv;
typedef __attribute__((address_space(3))) void* las_v;
__device__ __forceinline__ void async16(const u16* g, u16* l) {
  __builtin_amdgcn_global_load_lds((gas_cv)g, (las_v)l, 16, 0, 0);
}

// ---------------- prep kernels ----------------

__global__ void convert_x_kernel(const float* __restrict__ x, u16* __restrict__ xb) {
  size_t i = ((size_t)blockIdx.x * 256 + threadIdx.x) * 8;
  float4 v0 = *(const float4*)(x + i);
  float4 v1 = *(const float4*)(x + i + 4);
  uint4 o;
  o.x = pack_bf16x2(v0.x, v0.y);
  o.y = pack_bf16x2(v0.z, v0.w);
  o.z = pack_bf16x2(v1.x, v1.y);
  o.w = pack_bf16x2(v1.z, v1.w);
  *(uint4*)(xb + i) = o;
}

__global__ void transpose_w_kernel(const float* __restrict__ Wq, const float* __restrict__ Wk,
                                   const float* __restrict__ Wv, const float* __restrict__ Wo,
                                   u16* __restrict__ wqkvt, u16* __restrict__ wot) {
  __shared__ float tile[32][33];
  int z = blockIdx.z;
  const float* src = (z == 0) ? Wq : (z == 1) ? Wk : (z == 2) ? Wv : Wo;
  u16* dst = (z < 3) ? (wqkvt + (size_t)z * DMODEL * DMODEL) : wot;
  int c0 = blockIdx.x * 32, r0 = blockIdx.y * 32;
  int tx = threadIdx.x & 31, ty = threadIdx.x >> 5;
#pragma unroll
  for (int i = 0; i < 4; ++i)
    tile[ty + 8 * i][tx] = src[(size_t)(r0 + ty + 8 * i) * DMODEL + c0 + tx];
  __syncthreads();
#pragma unroll
  for (int i = 0; i < 4; ++i)
    dst[(size_t)(c0 + ty + 8 * i) * DMODEL + r0 + tx] = f32_to_bf16(tile[tx][ty + 8 * i]);
}

__global__ void concat_bias_kernel(const float* __restrict__ bq, const float* __restrict__ bk,
                                   const float* __restrict__ bv, float* __restrict__ bqkv) {
  int i = blockIdx.x * 256 + threadIdx.x;
  float v = (i < 1024) ? bq[i] : (i < 2048) ? bk[i - 1024] : bv[i - 2048];
  bqkv[i] = v;
}

// ---------------- GEMM v2: double-buffered LDS + counted-vmcnt (R12 win, unchanged) ----------------
template <int OUT_BF16, int FUSE_V>
__global__ __launch_bounds__(256) void gemm_bt_kernel(const u16* __restrict__ A,
                                                      const u16* __restrict__ Bt,
                                                      const float* __restrict__ bias,
                                                      void* __restrict__ Cout,
                                                      u16* __restrict__ vtout,
                                                      int M, int N, int K) {
  __shared__ u16 sA[2][128 * 32];
  __shared__ u16 sB[2][128 * 32];
  const int tid = threadIdx.x;
  const int wv = tid >> 6, lane = tid & 63;
  const int wr = wv >> 1, wc = wv & 1;
  const int col = lane & 15, quad = lane >> 4;
  const int m0 = blockIdx.x * 128;
  const int n0 = blockIdx.y * 128;

  f32x4 acc[4][4] = {};

  const int lr = tid >> 2;
  const int ls = tid & 3;
  const size_t a_base = (size_t)(m0 + lr) * K + ls * 8;
  const size_t b_base = (size_t)(n0 + lr) * K + ls * 8;
  const int wvo = (tid >> 6) << 9; // per-wave 1KB chunk offset (u16 units)

  // prologue: stage K-tile 0 into buffer 0 (4 loads, awaited at first loop-top wait)
  async16(A + a_base, sA[0] + wvo);
  async16(A + a_base + (size_t)64 * K, sA[0] + wvo + 2048);
  async16(Bt + b_base, sB[0] + wvo);
  async16(Bt + b_base + (size_t)64 * K, sB[0] + wvo + 2048);

  const int nit = K >> 5;
  for (int it = 0; it < nit; ++it) {
    const int cur = it & 1, nxt = cur ^ 1;

    if (it + 1 < nit) {
      const int k0 = (it + 1) << 5;
      async16(A + a_base + k0, sA[nxt] + wvo);
      async16(A + a_base + (size_t)64 * K + k0, sA[nxt] + wvo + 2048);
      async16(Bt + b_base + k0, sB[nxt] + wvo);
      async16(Bt + b_base + (size_t)64 * K + k0, sB[nxt] + wvo + 2048);
      asm volatile("s_waitcnt vmcnt(4)");
    } else {
      asm volatile("s_waitcnt vmcnt(0)");
    }
    __builtin_amdgcn_sched_barrier(0);
    __builtin_amdgcn_s_barrier(); // B1: K-tile it staged by ALL waves
    __builtin_amdgcn_sched_barrier(0);

    bf16x8 af[4], bfr[4];
#pragma unroll
    for (int i = 0; i < 4; ++i)
      af[i] = *(const bf16x8*)(sA[cur] + (wr * 64 + i * 16 + col) * 32 + quad * 8);
#pragma unroll
    for (int j = 0; j < 4; ++j)
      bfr[j] = *(const bf16x8*)(sB[cur] + (wc * 64 + j * 16 + col) * 32 + quad * 8);
#pragma unroll
    for (int i = 0; i < 4; ++i)
#pragma unroll
      for (int j = 0; j < 4; ++j)
        acc[i][j] = __builtin_amdgcn_mfma_f32_16x16x32_bf16(af[i], bfr[j], acc[i][j], 0, 0, 0);

    __builtin_amdgcn_sched_barrier(0);
    __builtin_amdgcn_s_barrier(); // B2: all waves done reading cur (no vmcnt drain)
    __builtin_amdgcn_sched_barrier(0);
  }

#pragma unroll
  for (int i = 0; i < 4; ++i) {
#pragma unroll
    for (int j = 0; j < 4; ++j) {
      int n = n0 + wc * 64 + j * 16 + col;
      float bia = bias[n];
      if (FUSE_V && n >= 2 * DMODEL) {
        // V column -> vt[((b*16+h)*64+dh)][s], 4 consecutive s packed into one 8B store
        const int hh = (n - 2 * DMODEL) >> 6, dh = n & 63;
        const int mb = m0 + wr * 64 + i * 16 + quad * 4;
        const int bb = mb >> 11, s0 = mb & 2047;
        uint2 pk;
        pk.x = pack_bf16x2(acc[i][j][0] + bia, acc[i][j][1] + bia);
        pk.y = pack_bf16x2(acc[i][j][2] + bia, acc[i][j][3] + bia);
        *(uint2*)(vtout + ((size_t)((bb * 16 + hh) * 64 + dh)) * SLEN + s0) = pk;
      } else {
        const int cstride = FUSE_V ? (2 * DMODEL) : N;
#pragma unroll
        for (int r = 0; r < 4; ++r) {
          int m = m0 + wr * 64 + i * 16 + quad * 4 + r;
          float v = acc[i][j][r] + bia;
          if (OUT_BF16)
            ((u16*)Cout)[(size_t)m * cstride + n] = f32_to_bf16(v);
          else
            ((float*)Cout)[(size_t)m * cstride + n] = v;
        }
      }
    }
  }
}

// ---------------- flash attention v17: 4 blocks/CU (single strip per wave) ----------------
// R12 counters: attn FETCH 24.6MB (XCD grouping near-ideal), HBM 6.5%, MfmaUtil 17.8,
// VALUBusy 44, Occupancy 18.9% (2 blocks/CU) -> latency-bound, nothing saturated.
// The "occupancy is a non-lever" conclusion was built on invalid tests (v12 computed
// every strip TWICE + spilled). Clean test: grid (8,64)->(16,64); each wave owns ONE
// 32-row strip s = bx*4+wv (bijective over 64 strips/bh); nt = 2bx+2 block-uniform
// staging, nt_own = s/2+1 compute guard. Same total staged tiles (272/bh), same
// per-wave compute, but 4 blocks/CU (16 waves/CU). Non-uniform block durations
// (2..32 tiles) mitigated by heavy-first ordering (bx = 15-raw) + 4-deep backfill.
// launch_bounds(256,4): VGPR cap 128 >= 96 used (v12's spill was a 64-cap).
// Math/sync/swizzle byte-identical to v16. Same-bh XCD grouping preserved.
__global__ __launch_bounds__(256, 4) void attn_kernel(const u16* __restrict__ qk,
                                                      const u16* __restrict__ vt,
                                                      u16* __restrict__ out) {
  const int lid = blockIdx.y * 16 + blockIdx.x; // [0,1024)
  const int xcd = lid & 7;
  const int local = lid >> 3;            // [0,128)
  const int bh = xcd * 8 + (local & 7);  // same-bh blocks share XCD
  const int bx = 15 - (local >> 3);      // 0..15, heavy blocks (large bx) launch early
  const int b = bh >> 4, h = bh & 15;
  const int tid = threadIdx.x;
  const int wv = tid >> 6, lane = tid & 63;
  const int c = lane & 31, hi = lane >> 5;
  const int s = bx * 4 + wv; // strip id 0..63 (32 q-rows each)

  __shared__ u16 sK[2][64 * 64];
  __shared__ u16 sV[2][64 * 64];

  const u16* kbase = qk + ((size_t)(b * SLEN)) * (2 * DMODEL) + DMODEL + h * DHEAD;
  const u16* vbase = vt + ((size_t)bh * DHEAD) * SLEN;
  const float scl2 = 0.125f * 1.44269504088896f; // 1/sqrt(dh) * log2(e)

  // staging mapping: wave wv stages rows [wv*16, wv*16+16) of both tiles (2 calls each).
  // LDS[row][seg sgm] holds global seg (sgm ^ (row&7)).
  const int lrow = lane >> 3;
  const int sga = (lane & 7) ^ lrow;
  const int r0a = wv * 16, r0b = wv * 16 + 8;
  const int cs = c & 7;

  const int qbase = s * 32;
  const int nt_own = s / 2 + 1;
  const int nt = 2 * bx + 2; // block-uniform staging sweep (= max nt_own in block)

  // Q fragments (B operand): lane (c,hi) holds Q[qbase+c][ks*16 + hi*8 + e]
  const u16* qrow =
      qk + ((size_t)(b * SLEN + qbase + c)) * (2 * DMODEL) + h * DHEAD + hi * 8;
  bf16x8 aQ[4];
#pragma unroll
  for (int ks = 0; ks < 4; ++ks) aQ[ks] = *(const bf16x8*)(qrow + ks * 16);

  f32x16 accO[2] = {}; // [mdh]: O^T, col=q=c, row=dh=mdh*32+(r&3)+8*(r>>2)+4*hi
  float m2 = -1e30f, l_i = 0.0f;

  // prologue: stage tile 0 into buffer 0 (awaited at first loop-top wait)
  async16(kbase + (size_t)(r0a + lrow) * (2 * DMODEL) + sga * 8, sK[0] + r0a * 64);
  async16(kbase + (size_t)(r0b + lrow) * (2 * DMODEL) + sga * 8, sK[0] + r0b * 64);
  async16(vbase + (size_t)(r0a + lrow) * SLEN + sga * 8, sV[0] + r0a * 64);
  async16(vbase + (size_t)(r0b + lrow) * SLEN + sga * 8, sV[0] + r0b * 64);

  for (int t = 0; t < nt; ++t) {
    const int kv0 = t * 64;
    const int cur = t & 1, nxt = cur ^ 1;

    // issue prefetch of tile t+1, then wait only for tile t's 4 loads
    if (t + 1 < nt) {
      const int kvn = kv0 + 64;
      async16(kbase + (size_t)(kvn + r0a + lrow) * (2 * DMODEL) + sga * 8, sK[nxt] + r0a * 64);
      async16(kbase + (size_t)(kvn + r0b + lrow) * (2 * DMODEL) + sga * 8, sK[nxt] + r0b * 64);
      async16(vbase + (size_t)(r0a + lrow) * SLEN + kvn + sga * 8, sV[nxt] + r0a * 64);
      async16(vbase + (size_t)(r0b + lrow) * SLEN + kvn + sga * 8, sV[nxt] + r0b * 64);
      asm volatile("s_waitcnt vmcnt(4)");
    } else {
      asm volatile("s_waitcnt vmcnt(0)");
    }
    __builtin_amdgcn_sched_barrier(0);
    __builtin_amdgcn_s_barrier(); // B1: tile t staged by ALL waves
    __builtin_amdgcn_sched_barrier(0);

    if (t < nt_own) {
      const u16* sKc = sK[cur];
      const u16* sVc = sV[cur];
      // bK: K[kv=m*32+c][dh=ks*16+hi*8..+8) as one b128.
      // bV (sigma-mapped): element e holds V^T[dh=m*32+c][kv0+ks*16+4hi+(e&3)+8*(e>>2)]
      //   = two b64 chunks at +4*hi inside segs 2ks and 2ks+1.
      bf16x8 bK[2][4], bV[2][4];
#pragma unroll
      for (int m = 0; m < 2; ++m) {
        const int rb = (m * 32 + c) * 64;
#pragma unroll
        for (int ks = 0; ks < 4; ++ks) {
          bK[m][ks] = *(const bf16x8*)(sKc + rb + (((ks * 2 + hi) ^ cs) << 3));
          bf16x4 vlo = *(const bf16x4*)(sVc + rb + (((ks * 2) ^ cs) << 3) + 4 * hi);
          bf16x4 vhi = *(const bf16x4*)(sVc + rb + (((ks * 2 + 1) ^ cs) << 3) + 4 * hi);
          bV[m][ks] = __builtin_shufflevector(vlo, vhi, 0, 1, 2, 3, 4, 5, 6, 7);
        }
      }

      // S^T = K Q^T : accST[m] col=q=c, row=kv=m*32+(r&3)+8*(r>>2)+4*hi (raw)
      f32x16 accST[2] = {};
      __builtin_amdgcn_s_setprio(1);
#pragma unroll
      for (int ks = 0; ks < 4; ++ks)
#pragma unroll
        for (int m = 0; m < 2; ++m)
          accST[m] = __builtin_amdgcn_mfma_f32_32x32x16_bf16(bK[m][ks], aQ[ks],
                                                             accST[m], 0, 0, 0);
      __builtin_amdgcn_s_setprio(0);

      // causal mask on diagonal tile
      if (t == nt_own - 1) {
        const int q = qbase + c;
        const int kvh = kv0 + 4 * hi;
#pragma unroll
        for (int m = 0; m < 2; ++m)
#pragma unroll
          for (int r = 0; r < 16; ++r) {
            int kv = kvh + m * 32 + ((r & 3) + 8 * (r >> 2));
            if (kv > q) accST[m][r] = -1e30f;
          }
      }

      // online softmax (exp2 domain); full-row reduce = own 32 + partner via shfl^32
      float h0 = fmaxf(fmaxf(accST[0][0], accST[0][1]), fmaxf(accST[0][2], accST[0][3]));
      float h1 = fmaxf(fmaxf(accST[0][4], accST[0][5]), fmaxf(accST[0][6], accST[0][7]));
      float h2 = fmaxf(fmaxf(accST[0][8], accST[0][9]), fmaxf(accST[0][10], accST[0][11]));
      float h3 = fmaxf(fmaxf(accST[0][12], accST[0][13]), fmaxf(accST[0][14], accST[0][15]));
      float h4 = fmaxf(fmaxf(accST[1][0], accST[1][1]), fmaxf(accST[1][2], accST[1][3]));
      float h5 = fmaxf(fmaxf(accST[1][4], accST[1][5]), fmaxf(accST[1][6], accST[1][7]));
      float h6 = fmaxf(fmaxf(accST[1][8], accST[1][9]), fmaxf(accST[1][10], accST[1][11]));
      float h7 = fmaxf(fmaxf(accST[1][12], accST[1][13]), fmaxf(accST[1][14], accST[1][15]));
      float rmax = fmaxf(fmaxf(fmaxf(h0, h1), fmaxf(h2, h3)),
                         fmaxf(fmaxf(h4, h5), fmaxf(h6, h7)));
      rmax = fmaxf(rmax, __shfl_xor(rmax, 32));
      float rmaxs = rmax * scl2;
      const bool noresc = __all(rmaxs <= m2);
      float mnew = noresc ? m2 : fmaxf(m2, rmaxs);
      float alpha = noresc ? 1.0f : EXP2(m2 - mnew);
      m2 = mnew;

      float s0 = 0.f, s1 = 0.f, s2s = 0.f, s3 = 0.f;
#pragma unroll
      for (int m = 0; m < 2; ++m) {
#pragma unroll
        for (int r = 0; r < 16; r += 4) {
          float p0 = EXP2(__builtin_fmaf(accST[m][r + 0], scl2, -mnew));
          float p1 = EXP2(__builtin_fmaf(accST[m][r + 1], scl2, -mnew));
          float p2 = EXP2(__builtin_fmaf(accST[m][r + 2], scl2, -mnew));
          float p3 = EXP2(__builtin_fmaf(accST[m][r + 3], scl2, -mnew));
          accST[m][r + 0] = p0;
          accST[m][r + 1] = p1;
          accST[m][r + 2] = p2;
          accST[m][r + 3] = p3;
          s0 += p0;
          s1 += p1;
          s2s += p2;
          s3 += p3;
        }
      }
      float sacc = (s0 + s1) + (s2s + s3);
      sacc += __shfl_xor(sacc, 32);
      if (noresc) {
        l_i += sacc;
      } else {
        l_i = l_i * alpha + sacc;
#pragma unroll
        for (int m = 0; m < 2; ++m)
#pragma unroll
          for (int r = 0; r < 16; ++r) accO[m][r] *= alpha;
      }

      // P -> B-fragments, sigma-mapped: each lane packs its OWN rows in natural order.
      // aP[2m+s'] element e = P[(2m+s')*16 + 4hi + (e&3) + 8*(e>>2)][q=c] = accST[m][8s'+e].
      bf16x8 aP[4];
#pragma unroll
      for (int m = 0; m < 2; ++m)
#pragma unroll
        for (int sp = 0; sp < 2; ++sp) {
          union {
            uint4 u;
            bf16x8 v;
          } cvt;
          cvt.u.x = pack_trunc(accST[m][8 * sp + 0], accST[m][8 * sp + 1]);
          cvt.u.y = pack_trunc(accST[m][8 * sp + 2], accST[m][8 * sp + 3]);
          cvt.u.z = pack_trunc(accST[m][8 * sp + 4], accST[m][8 * sp + 5]);
          cvt.u.w = pack_trunc(accST[m][8 * sp + 6], accST[m][8 * sp + 7]);
          aP[m * 2 + sp] = cvt.v;
        }

      // O^T += V^T P^T (A and B share the sigma k-permutation per 16-slice)
      __builtin_amdgcn_s_setprio(1);
#pragma unroll
      for (int ks = 0; ks < 4; ++ks)
#pragma unroll
        for (int m = 0; m < 2; ++m)
          accO[m] = __builtin_amdgcn_mfma_f32_32x32x16_bf16(bV[m][ks], aP[ks],
                                                            accO[m], 0, 0, 0);
      __builtin_amdgcn_s_setprio(0);
    }

    __builtin_amdgcn_sched_barrier(0);
    __builtin_amdgcn_s_barrier(); // B2: all waves done reading cur (no vmcnt drain)
    __builtin_amdgcn_sched_barrier(0);
  }

  // epilogue: O^T col=q row=dh -> out[q][dh], packed dwordx2 stores
  {
    float rl = 1.0f / l_i;
    size_t rowoff =
        ((size_t)(b * SLEN + qbase + c)) * DMODEL + h * DHEAD + 4 * hi;
#pragma unroll
    for (int m = 0; m < 2; ++m)
#pragma unroll
      for (int j = 0; j < 4; ++j) {
        uint2 pk;
        pk.x = pack_round(accO[m][4 * j + 0] * rl, accO[m][4 * j + 1] * rl);
        pk.y = pack_round(accO[m][4 * j + 2] * rl, accO[m][4 * j + 3] * rl);
        *(uint2*)(out + rowoff + m * 32 + 8 * j) = pk;
      }
  }
}

// ---------------- launch ----------------

extern "C" void kernel_launch(void* const* d_in, const int* in_sizes, int n_in,
                              void* d_out, int out_size, void* d_ws, size_t ws_size,
                              hipStream_t stream) {
  const float* x = (const float*)d_in[0];
  const float* Wq = (const float*)d_in[1];
  const float* bq = (const float*)d_in[2];
  const float* Wk = (const float*)d_in[3];
  const float* bk = (const float*)d_in[4];
  const float* Wv = (const float*)d_in[5];
  const float* bv = (const float*)d_in[6];
  const float* Wo = (const float*)d_in[7];
  const float* bo = (const float*)d_in[8];

  char* ws = (char*)d_ws;
  u16* xb = (u16*)ws;                              // 16 MB
  u16* wqkvt = (u16*)(ws + ((size_t)16 << 20));    // 6 MB
  u16* wot = (u16*)(ws + ((size_t)22 << 20));      // 2 MB
  u16* qk = (u16*)(ws + ((size_t)24 << 20));       // 32 MB (Q|K, row stride 2048)
  u16* vtp = (u16*)(ws + ((size_t)56 << 20));      // 16 MB (V transposed, fused write)
  u16* attnO = (u16*)(ws + ((size_t)72 << 20));    // 16 MB
  float* bqkv = (float*)(ws + ((size_t)88 << 20)); // 12 KB

  convert_x_kernel<<<4096, 256, 0, stream>>>(x, xb);
  transpose_w_kernel<<<dim3(32, 32, 4), 256, 0, stream>>>(Wq, Wk, Wv, Wo, wqkvt, wot);
  concat_bias_kernel<<<12, 256, 0, stream>>>(bq, bk, bv, bqkv);
  gemm_bt_kernel<1, 1><<<dim3(64, 24), 256, 0, stream>>>(xb, wqkvt, bqkv, (void*)qk, vtp,
                                                         MROWS, 3 * DMODEL, DMODEL);
  attn_kernel<<<dim3(16, 64), 256, 0, stream>>>(qk, vtp, attnO);
  gemm_bt_kernel<0, 0><<<dim3(64, 8), 256, 0, stream>>>(attnO, wot, bo, d_out, nullptr,
                                                        MROWS, DMODEL, DMODEL);
}

// Round 14
// 261.811 us; speedup vs baseline: 1.3405x; 1.3405x over previous
//
#include <hip/hip_runtime.h>

typedef unsigned short u16;
typedef unsigned int u32;
typedef __bf16 bf16x4 __attribute__((ext_vector_type(4)));
typedef __bf16 bf16x8 __attribute__((ext_vector_type(8)));
typedef float f32x4 __attribute__((ext_vector_type(4)));
typedef float f32x16 __attribute__((ext_vector_type(16)));

#define BATCH 4
#define SLEN 2048
#define DMODEL 1024
#define NHEAD 16
#define DHEAD 64
#define MROWS (BATCH * SLEN) /* 8192 */

__device__ __forceinline__ u16 f32_to_bf16(float f) {
  u32 u = __float_as_uint(f);
  u32 r = (u + 0x7FFFu + ((u >> 16) & 1u)) >> 16;
  return (u16)r;
}
__device__ __forceinline__ u32 pack_bf16x2(float a, float b) {
  return (u32)f32_to_bf16(a) | ((u32)f32_to_bf16(b) << 16);
}

// pack two f32 -> two bf16 (truncate), 1 v_perm_b32
__device__ __forceinline__ u32 pack_trunc(float lo, float hi) {
#if __has_builtin(__builtin_amdgcn_perm)
  return __builtin_amdgcn_perm(__float_as_uint(hi), __float_as_uint(lo), 0x07060302u);
#else
  return (__float_as_uint(hi) & 0xFFFF0000u) | (__float_as_uint(lo) >> 16);
#endif
}
// pack with round-half-up (epilogue)
__device__ __forceinline__ u32 pack_round(float lo, float hi) {
  u32 ul = __float_as_uint(lo) + 0x8000u;
  u32 uh = __float_as_uint(hi) + 0x8000u;
#if __has_builtin(__builtin_amdgcn_perm)
  return __builtin_amdgcn_perm(uh, ul, 0x07060302u);
#else
  return (uh & 0xFFFF0000u) | (ul >> 16);
#endif
}

#if __has_builtin(__builtin_amdgcn_exp2f)
#define EXP2(x) __builtin_amdgcn_exp2f(x)
#else
#define EXP2(x) exp2f(x)
#endif

// async global->LDS, 16 B per lane; lds dest = wave-uniform base + lane*16
typedef const __attribute__((address_space(1))) void* gas_cv;
typedef __attribute__((address_space(3))) void* las_v;
__device__ __forceinline__ void async16(const u16* g, u16* l) {
  __builtin_amdgcn_global_load_lds((gas_cv)g, (las_v)l, 16, 0, 0);
}

// ---------------- prep kernels ----------------

__global__ void convert_x_kernel(const float* __restrict__ x, u16* __restrict__ xb) {
  size_t i = ((size_t)blockIdx.x * 256 + threadIdx.x) * 8;
  float4 v0 = *(const float4*)(x + i);
  float4 v1 = *(const float4*)(x + i + 4);
  uint4 o;
  o.x = pack_bf16x2(v0.x, v0.y);
  o.y = pack_bf16x2(v0.z, v0.w);
  o.z = pack_bf16x2(v1.x, v1.y);
  o.w = pack_bf16x2(v1.z, v1.w);
  *(uint4*)(xb + i) = o;
}

__global__ void transpose_w_kernel(const float* __restrict__ Wq, const float* __restrict__ Wk,
                                   const float* __restrict__ Wv, const float* __restrict__ Wo,
                                   u16* __restrict__ wqkvt, u16* __restrict__ wot) {
  __shared__ float tile[32][33];
  int z = blockIdx.z;
  const float* src = (z == 0) ? Wq : (z == 1) ? Wk : (z == 2) ? Wv : Wo;
  u16* dst = (z < 3) ? (wqkvt + (size_t)z * DMODEL * DMODEL) : wot;
  int c0 = blockIdx.x * 32, r0 = blockIdx.y * 32;
  int tx = threadIdx.x & 31, ty = threadIdx.x >> 5;
#pragma unroll
  for (int i = 0; i < 4; ++i)
    tile[ty + 8 * i][tx] = src[(size_t)(r0 + ty + 8 * i) * DMODEL + c0 + tx];
  __syncthreads();
#pragma unroll
  for (int i = 0; i < 4; ++i)
    dst[(size_t)(c0 + ty + 8 * i) * DMODEL + r0 + tx] = f32_to_bf16(tile[tx][ty + 8 * i]);
}

__global__ void concat_bias_kernel(const float* __restrict__ bq, const float* __restrict__ bk,
                                   const float* __restrict__ bv, float* __restrict__ bqkv) {
  int i = blockIdx.x * 256 + threadIdx.x;
  float v = (i < 1024) ? bq[i] : (i < 2048) ? bk[i - 1024] : bv[i - 2048];
  bqkv[i] = v;
}

// ---------------- GEMM v2: double-buffered LDS + counted-vmcnt (R12 win, unchanged) ----------------
template <int OUT_BF16, int FUSE_V>
__global__ __launch_bounds__(256) void gemm_bt_kernel(const u16* __restrict__ A,
                                                      const u16* __restrict__ Bt,
                                                      const float* __restrict__ bias,
                                                      void* __restrict__ Cout,
                                                      u16* __restrict__ vtout,
                                                      int M, int N, int K) {
  __shared__ u16 sA[2][128 * 32];
  __shared__ u16 sB[2][128 * 32];
  const int tid = threadIdx.x;
  const int wv = tid >> 6, lane = tid & 63;
  const int wr = wv >> 1, wc = wv & 1;
  const int col = lane & 15, quad = lane >> 4;
  const int m0 = blockIdx.x * 128;
  const int n0 = blockIdx.y * 128;

  f32x4 acc[4][4] = {};

  const int lr = tid >> 2;
  const int ls = tid & 3;
  const size_t a_base = (size_t)(m0 + lr) * K + ls * 8;
  const size_t b_base = (size_t)(n0 + lr) * K + ls * 8;
  const int wvo = (tid >> 6) << 9; // per-wave 1KB chunk offset (u16 units)

  // prologue: stage K-tile 0 into buffer 0 (4 loads, awaited at first loop-top wait)
  async16(A + a_base, sA[0] + wvo);
  async16(A + a_base + (size_t)64 * K, sA[0] + wvo + 2048);
  async16(Bt + b_base, sB[0] + wvo);
  async16(Bt + b_base + (size_t)64 * K, sB[0] + wvo + 2048);

  const int nit = K >> 5;
  for (int it = 0; it < nit; ++it) {
    const int cur = it & 1, nxt = cur ^ 1;

    if (it + 1 < nit) {
      const int k0 = (it + 1) << 5;
      async16(A + a_base + k0, sA[nxt] + wvo);
      async16(A + a_base + (size_t)64 * K + k0, sA[nxt] + wvo + 2048);
      async16(Bt + b_base + k0, sB[nxt] + wvo);
      async16(Bt + b_base + (size_t)64 * K + k0, sB[nxt] + wvo + 2048);
      asm volatile("s_waitcnt vmcnt(4)");
    } else {
      asm volatile("s_waitcnt vmcnt(0)");
    }
    __builtin_amdgcn_sched_barrier(0);
    __builtin_amdgcn_s_barrier(); // B1: K-tile it staged by ALL waves
    __builtin_amdgcn_sched_barrier(0);

    bf16x8 af[4], bfr[4];
#pragma unroll
    for (int i = 0; i < 4; ++i)
      af[i] = *(const bf16x8*)(sA[cur] + (wr * 64 + i * 16 + col) * 32 + quad * 8);
#pragma unroll
    for (int j = 0; j < 4; ++j)
      bfr[j] = *(const bf16x8*)(sB[cur] + (wc * 64 + j * 16 + col) * 32 + quad * 8);
#pragma unroll
    for (int i = 0; i < 4; ++i)
#pragma unroll
      for (int j = 0; j < 4; ++j)
        acc[i][j] = __builtin_amdgcn_mfma_f32_16x16x32_bf16(af[i], bfr[j], acc[i][j], 0, 0, 0);

    __builtin_amdgcn_sched_barrier(0);
    __builtin_amdgcn_s_barrier(); // B2: all waves done reading cur (no vmcnt drain)
    __builtin_amdgcn_sched_barrier(0);
  }

#pragma unroll
  for (int i = 0; i < 4; ++i) {
#pragma unroll
    for (int j = 0; j < 4; ++j) {
      int n = n0 + wc * 64 + j * 16 + col;
      float bia = bias[n];
      if (FUSE_V && n >= 2 * DMODEL) {
        // V column -> vt[((b*16+h)*64+dh)][s], 4 consecutive s packed into one 8B store
        const int hh = (n - 2 * DMODEL) >> 6, dh = n & 63;
        const int mb = m0 + wr * 64 + i * 16 + quad * 4;
        const int bb = mb >> 11, s0 = mb & 2047;
        uint2 pk;
        pk.x = pack_bf16x2(acc[i][j][0] + bia, acc[i][j][1] + bia);
        pk.y = pack_bf16x2(acc[i][j][2] + bia, acc[i][j][3] + bia);
        *(uint2*)(vtout + ((size_t)((bb * 16 + hh) * 64 + dh)) * SLEN + s0) = pk;
      } else {
        const int cstride = FUSE_V ? (2 * DMODEL) : N;
#pragma unroll
        for (int r = 0; r < 4; ++r) {
          int m = m0 + wr * 64 + i * 16 + quad * 4 + r;
          float v = acc[i][j][r] + bia;
          if (OUT_BF16)
            ((u16*)Cout)[(size_t)m * cstride + n] = f32_to_bf16(v);
          else
            ((float*)Cout)[(size_t)m * cstride + n] = v;
        }
      }
    }
  }
}

// ---------------- flash attention v18: grid (16,64), NO register cap ----------------
// v17 post-mortem: __launch_bounds__(256,4) empirically imposes a 64-VGPR cap on this
// toolchain (v12's (512,4) did too) -> spills (WRITE 16->153MB) -> 160us. The cap is
// UNNECESSARY: at 96 VGPR the HW already allows 4 waves/SIMD (occupancy halves at
// 64/128/256 per m69) and 32KB LDS/block allows 4 blocks/CU (128<=160KB).
// v18 = v17's grid (16,64) single-strip-per-wave decomposition + v16's
// __launch_bounds__(256,2) (a MINIMUM hint; compiler emits ~96 VGPR as in v16).
// Everything else byte-identical to v17 (which passed validation).
__global__ __launch_bounds__(256, 2) void attn_kernel(const u16* __restrict__ qk,
                                                      const u16* __restrict__ vt,
                                                      u16* __restrict__ out) {
  const int lid = blockIdx.y * 16 + blockIdx.x; // [0,1024)
  const int xcd = lid & 7;
  const int local = lid >> 3;            // [0,128)
  const int bh = xcd * 8 + (local & 7);  // same-bh blocks share XCD
  const int bx = 15 - (local >> 3);      // 0..15, heavy blocks (large bx) launch early
  const int b = bh >> 4, h = bh & 15;
  const int tid = threadIdx.x;
  const int wv = tid >> 6, lane = tid & 63;
  const int c = lane & 31, hi = lane >> 5;
  const int s = bx * 4 + wv; // strip id 0..63 (32 q-rows each)

  __shared__ u16 sK[2][64 * 64];
  __shared__ u16 sV[2][64 * 64];

  const u16* kbase = qk + ((size_t)(b * SLEN)) * (2 * DMODEL) + DMODEL + h * DHEAD;
  const u16* vbase = vt + ((size_t)bh * DHEAD) * SLEN;
  const float scl2 = 0.125f * 1.44269504088896f; // 1/sqrt(dh) * log2(e)

  // staging mapping: wave wv stages rows [wv*16, wv*16+16) of both tiles (2 calls each).
  // LDS[row][seg sgm] holds global seg (sgm ^ (row&7)).
  const int lrow = lane >> 3;
  const int sga = (lane & 7) ^ lrow;
  const int r0a = wv * 16, r0b = wv * 16 + 8;
  const int cs = c & 7;

  const int qbase = s * 32;
  const int nt_own = s / 2 + 1;
  const int nt = 2 * bx + 2; // block-uniform staging sweep (= max nt_own in block)

  // Q fragments (B operand): lane (c,hi) holds Q[qbase+c][ks*16 + hi*8 + e]
  const u16* qrow =
      qk + ((size_t)(b * SLEN + qbase + c)) * (2 * DMODEL) + h * DHEAD + hi * 8;
  bf16x8 aQ[4];
#pragma unroll
  for (int ks = 0; ks < 4; ++ks) aQ[ks] = *(const bf16x8*)(qrow + ks * 16);

  f32x16 accO[2] = {}; // [mdh]: O^T, col=q=c, row=dh=mdh*32+(r&3)+8*(r>>2)+4*hi
  float m2 = -1e30f, l_i = 0.0f;

  // prologue: stage tile 0 into buffer 0 (awaited at first loop-top wait)
  async16(kbase + (size_t)(r0a + lrow) * (2 * DMODEL) + sga * 8, sK[0] + r0a * 64);
  async16(kbase + (size_t)(r0b + lrow) * (2 * DMODEL) + sga * 8, sK[0] + r0b * 64);
  async16(vbase + (size_t)(r0a + lrow) * SLEN + sga * 8, sV[0] + r0a * 64);
  async16(vbase + (size_t)(r0b + lrow) * SLEN + sga * 8, sV[0] + r0b * 64);

  for (int t = 0; t < nt; ++t) {
    const int kv0 = t * 64;
    const int cur = t & 1, nxt = cur ^ 1;

    // issue prefetch of tile t+1, then wait only for tile t's 4 loads
    if (t + 1 < nt) {
      const int kvn = kv0 + 64;
      async16(kbase + (size_t)(kvn + r0a + lrow) * (2 * DMODEL) + sga * 8, sK[nxt] + r0a * 64);
      async16(kbase + (size_t)(kvn + r0b + lrow) * (2 * DMODEL) + sga * 8, sK[nxt] + r0b * 64);
      async16(vbase + (size_t)(r0a + lrow) * SLEN + kvn + sga * 8, sV[nxt] + r0a * 64);
      async16(vbase + (size_t)(r0b + lrow) * SLEN + kvn + sga * 8, sV[nxt] + r0b * 64);
      asm volatile("s_waitcnt vmcnt(4)");
    } else {
      asm volatile("s_waitcnt vmcnt(0)");
    }
    __builtin_amdgcn_sched_barrier(0);
    __builtin_amdgcn_s_barrier(); // B1: tile t staged by ALL waves
    __builtin_amdgcn_sched_barrier(0);

    if (t < nt_own) {
      const u16* sKc = sK[cur];
      const u16* sVc = sV[cur];
      // bK: K[kv=m*32+c][dh=ks*16+hi*8..+8) as one b128.
      // bV (sigma-mapped): element e holds V^T[dh=m*32+c][kv0+ks*16+4hi+(e&3)+8*(e>>2)]
      //   = two b64 chunks at +4*hi inside segs 2ks and 2ks+1.
      bf16x8 bK[2][4], bV[2][4];
#pragma unroll
      for (int m = 0; m < 2; ++m) {
        const int rb = (m * 32 + c) * 64;
#pragma unroll
        for (int ks = 0; ks < 4; ++ks) {
          bK[m][ks] = *(const bf16x8*)(sKc + rb + (((ks * 2 + hi) ^ cs) << 3));
          bf16x4 vlo = *(const bf16x4*)(sVc + rb + (((ks * 2) ^ cs) << 3) + 4 * hi);
          bf16x4 vhi = *(const bf16x4*)(sVc + rb + (((ks * 2 + 1) ^ cs) << 3) + 4 * hi);
          bV[m][ks] = __builtin_shufflevector(vlo, vhi, 0, 1, 2, 3, 4, 5, 6, 7);
        }
      }

      // S^T = K Q^T : accST[m] col=q=c, row=kv=m*32+(r&3)+8*(r>>2)+4*hi (raw)
      f32x16 accST[2] = {};
      __builtin_amdgcn_s_setprio(1);
#pragma unroll
      for (int ks = 0; ks < 4; ++ks)
#pragma unroll
        for (int m = 0; m < 2; ++m)
          accST[m] = __builtin_amdgcn_mfma_f32_32x32x16_bf16(bK[m][ks], aQ[ks],
                                                             accST[m], 0, 0, 0);
      __builtin_amdgcn_s_setprio(0);

      // causal mask on diagonal tile
      if (t == nt_own - 1) {
        const int q = qbase + c;
        const int kvh = kv0 + 4 * hi;
#pragma unroll
        for (int m = 0; m < 2; ++m)
#pragma unroll
          for (int r = 0; r < 16; ++r) {
            int kv = kvh + m * 32 + ((r & 3) + 8 * (r >> 2));
            if (kv > q) accST[m][r] = -1e30f;
          }
      }

      // online softmax (exp2 domain); full-row reduce = own 32 + partner via shfl^32
      float h0 = fmaxf(fmaxf(accST[0][0], accST[0][1]), fmaxf(accST[0][2], accST[0][3]));
      float h1 = fmaxf(fmaxf(accST[0][4], accST[0][5]), fmaxf(accST[0][6], accST[0][7]));
      float h2 = fmaxf(fmaxf(accST[0][8], accST[0][9]), fmaxf(accST[0][10], accST[0][11]));
      float h3 = fmaxf(fmaxf(accST[0][12], accST[0][13]), fmaxf(accST[0][14], accST[0][15]));
      float h4 = fmaxf(fmaxf(accST[1][0], accST[1][1]), fmaxf(accST[1][2], accST[1][3]));
      float h5 = fmaxf(fmaxf(accST[1][4], accST[1][5]), fmaxf(accST[1][6], accST[1][7]));
      float h6 = fmaxf(fmaxf(accST[1][8], accST[1][9]), fmaxf(accST[1][10], accST[1][11]));
      float h7 = fmaxf(fmaxf(accST[1][12], accST[1][13]), fmaxf(accST[1][14], accST[1][15]));
      float rmax = fmaxf(fmaxf(fmaxf(h0, h1), fmaxf(h2, h3)),
                         fmaxf(fmaxf(h4, h5), fmaxf(h6, h7)));
      rmax = fmaxf(rmax, __shfl_xor(rmax, 32));
      float rmaxs = rmax * scl2;
      const bool noresc = __all(rmaxs <= m2);
      float mnew = noresc ? m2 : fmaxf(m2, rmaxs);
      float alpha = noresc ? 1.0f : EXP2(m2 - mnew);
      m2 = mnew;

      float s0 = 0.f, s1 = 0.f, s2s = 0.f, s3 = 0.f;
#pragma unroll
      for (int m = 0; m < 2; ++m) {
#pragma unroll
        for (int r = 0; r < 16; r += 4) {
          float p0 = EXP2(__builtin_fmaf(accST[m][r + 0], scl2, -mnew));
          float p1 = EXP2(__builtin_fmaf(accST[m][r + 1], scl2, -mnew));
          float p2 = EXP2(__builtin_fmaf(accST[m][r + 2], scl2, -mnew));
          float p3 = EXP2(__builtin_fmaf(accST[m][r + 3], scl2, -mnew));
          accST[m][r + 0] = p0;
          accST[m][r + 1] = p1;
          accST[m][r + 2] = p2;
          accST[m][r + 3] = p3;
          s0 += p0;
          s1 += p1;
          s2s += p2;
          s3 += p3;
        }
      }
      float sacc = (s0 + s1) + (s2s + s3);
      sacc += __shfl_xor(sacc, 32);
      if (noresc) {
        l_i += sacc;
      } else {
        l_i = l_i * alpha + sacc;
#pragma unroll
        for (int m = 0; m < 2; ++m)
#pragma unroll
          for (int r = 0; r < 16; ++r) accO[m][r] *= alpha;
      }

      // P -> B-fragments, sigma-mapped: each lane packs its OWN rows in natural order.
      // aP[2m+s'] element e = P[(2m+s')*16 + 4hi + (e&3) + 8*(e>>2)][q=c] = accST[m][8s'+e].
      bf16x8 aP[4];
#pragma unroll
      for (int m = 0; m < 2; ++m)
#pragma unroll
        for (int sp = 0; sp < 2; ++sp) {
          union {
            uint4 u;
            bf16x8 v;
          } cvt;
          cvt.u.x = pack_trunc(accST[m][8 * sp + 0], accST[m][8 * sp + 1]);
          cvt.u.y = pack_trunc(accST[m][8 * sp + 2], accST[m][8 * sp + 3]);
          cvt.u.z = pack_trunc(accST[m][8 * sp + 4], accST[m][8 * sp + 5]);
          cvt.u.w = pack_trunc(accST[m][8 * sp + 6], accST[m][8 * sp + 7]);
          aP[m * 2 + sp] = cvt.v;
        }

      // O^T += V^T P^T (A and B share the sigma k-permutation per 16-slice)
      __builtin_amdgcn_s_setprio(1);
#pragma unroll
      for (int ks = 0; ks < 4; ++ks)
#pragma unroll
        for (int m = 0; m < 2; ++m)
          accO[m] = __builtin_amdgcn_mfma_f32_32x32x16_bf16(bV[m][ks], aP[ks],
                                                            accO[m], 0, 0, 0);
      __builtin_amdgcn_s_setprio(0);
    }

    __builtin_amdgcn_sched_barrier(0);
    __builtin_amdgcn_s_barrier(); // B2: all waves done reading cur (no vmcnt drain)
    __builtin_amdgcn_sched_barrier(0);
  }

  // epilogue: O^T col=q row=dh -> out[q][dh], packed dwordx2 stores
  {
    float rl = 1.0f / l_i;
    size_t rowoff =
        ((size_t)(b * SLEN + qbase + c)) * DMODEL + h * DHEAD + 4 * hi;
#pragma unroll
    for (int m = 0; m < 2; ++m)
#pragma unroll
      for (int j = 0; j < 4; ++j) {
        uint2 pk;
        pk.x = pack_round(accO[m][4 * j + 0] * rl, accO[m][4 * j + 1] * rl);
        pk.y = pack_round(accO[m][4 * j + 2] * rl, accO[m][4 * j + 3] * rl);
        *(uint2*)(out + rowoff + m * 32 + 8 * j) = pk;
      }
  }
}

// ---------------- launch ----------------

extern "C" void kernel_launch(void* const* d_in, const int* in_sizes, int n_in,
                              void* d_out, int out_size, void* d_ws, size_t ws_size,
                              hipStream_t stream) {
  const float* x = (const float*)d_in[0];
  const float* Wq = (const float*)d_in[1];
  const float* bq = (const float*)d_in[2];
  const float* Wk = (const float*)d_in[3];
  const float* bk = (const float*)d_in[4];
  const float* Wv = (const float*)d_in[5];
  const float* bv = (const float*)d_in[6];
  const float* Wo = (const float*)d_in[7];
  const float* bo = (const float*)d_in[8];

  char* ws = (char*)d_ws;
  u16* xb = (u16*)ws;                              // 16 MB
  u16* wqkvt = (u16*)(ws + ((size_t)16 << 20));    // 6 MB
  u16* wot = (u16*)(ws + ((size_t)22 << 20));      // 2 MB
  u16* qk = (u16*)(ws + ((size_t)24 << 20));       // 32 MB (Q|K, row stride 2048)
  u16* vtp = (u16*)(ws + ((size_t)56 << 20));      // 16 MB (V transposed, fused write)
  u16* attnO = (u16*)(ws + ((size_t)72 << 20));    // 16 MB
  float* bqkv = (float*)(ws + ((size_t)88 << 20)); // 12 KB

  convert_x_kernel<<<4096, 256, 0, stream>>>(x, xb);
  transpose_w_kernel<<<dim3(32, 32, 4), 256, 0, stream>>>(Wq, Wk, Wv, Wo, wqkvt, wot);
  concat_bias_kernel<<<12, 256, 0, stream>>>(bq, bk, bv, bqkv);
  gemm_bt_kernel<1, 1><<<dim3(64, 24), 256, 0, stream>>>(xb, wqkvt, bqkv, (void*)qk, vtp,
                                                         MROWS, 3 * DMODEL, DMODEL);
  attn_kernel<<<dim3(16, 64), 256, 0, stream>>>(qk, vtp, attnO);
  gemm_bt_kernel<0, 0><<<dim3(64, 8), 256, 0, stream>>>(attnO, wot, bo, d_out, nullptr,
                                                        MROWS, DMODEL, DMODEL);
}

// Round 15
// 258.774 us; speedup vs baseline: 1.3562x; 1.0117x over previous
//
#include <hip/hip_runtime.h>

typedef unsigned short u16;
typedef unsigned int u32;
typedef __bf16 bf16x4 __attribute__((ext_vector_type(4)));
typedef __bf16 bf16x8 __attribute__((ext_vector_type(8)));
typedef float f32x4 __attribute__((ext_vector_type(4)));
typedef float f32x16 __attribute__((ext_vector_type(16)));

#define BATCH 4
#define SLEN 2048
#define DMODEL 1024
#define NHEAD 16
#define DHEAD 64
#define MROWS (BATCH * SLEN) /* 8192 */

__device__ __forceinline__ u16 f32_to_bf16(float f) {
  u32 u = __float_as_uint(f);
  u32 r = (u + 0x7FFFu + ((u >> 16) & 1u)) >> 16;
  return (u16)r;
}
__device__ __forceinline__ u32 pack_bf16x2(float a, float b) {
  return (u32)f32_to_bf16(a) | ((u32)f32_to_bf16(b) << 16);
}

// pack two f32 -> two bf16 (truncate), 1 v_perm_b32
__device__ __forceinline__ u32 pack_trunc(float lo, float hi) {
#if __has_builtin(__builtin_amdgcn_perm)
  return __builtin_amdgcn_perm(__float_as_uint(hi), __float_as_uint(lo), 0x07060302u);
#else
  return (__float_as_uint(hi) & 0xFFFF0000u) | (__float_as_uint(lo) >> 16);
#endif
}
// pack with round-half-up (epilogue)
__device__ __forceinline__ u32 pack_round(float lo, float hi) {
  u32 ul = __float_as_uint(lo) + 0x8000u;
  u32 uh = __float_as_uint(hi) + 0x8000u;
#if __has_builtin(__builtin_amdgcn_perm)
  return __builtin_amdgcn_perm(uh, ul, 0x07060302u);
#else
  return (uh & 0xFFFF0000u) | (ul >> 16);
#endif
}

#if __has_builtin(__builtin_amdgcn_exp2f)
#define EXP2(x) __builtin_amdgcn_exp2f(x)
#else
#define EXP2(x) exp2f(x)
#endif

// async global->LDS, 16 B per lane; lds dest = wave-uniform base + lane*16
typedef const __attribute__((address_space(1))) void* gas_cv;
typedef __attribute__((address_space(3))) void* las_v;
__device__ __forceinline__ void async16(const u16* g, u16* l) {
  __builtin_amdgcn_global_load_lds((gas_cv)g, (las_v)l, 16, 0, 0);
}

// ---------------- prep kernels ----------------

__global__ void convert_x_kernel(const float* __restrict__ x, u16* __restrict__ xb) {
  size_t i = ((size_t)blockIdx.x * 256 + threadIdx.x) * 8;
  float4 v0 = *(const float4*)(x + i);
  float4 v1 = *(const float4*)(x + i + 4);
  uint4 o;
  o.x = pack_bf16x2(v0.x, v0.y);
  o.y = pack_bf16x2(v0.z, v0.w);
  o.z = pack_bf16x2(v1.x, v1.y);
  o.w = pack_bf16x2(v1.z, v1.w);
  *(uint4*)(xb + i) = o;
}

__global__ void transpose_w_kernel(const float* __restrict__ Wq, const float* __restrict__ Wk,
                                   const float* __restrict__ Wv, const float* __restrict__ Wo,
                                   u16* __restrict__ wqkvt, u16* __restrict__ wot) {
  __shared__ float tile[32][33];
  int z = blockIdx.z;
  const float* src = (z == 0) ? Wq : (z == 1) ? Wk : (z == 2) ? Wv : Wo;
  u16* dst = (z < 3) ? (wqkvt + (size_t)z * DMODEL * DMODEL) : wot;
  int c0 = blockIdx.x * 32, r0 = blockIdx.y * 32;
  int tx = threadIdx.x & 31, ty = threadIdx.x >> 5;
#pragma unroll
  for (int i = 0; i < 4; ++i)
    tile[ty + 8 * i][tx] = src[(size_t)(r0 + ty + 8 * i) * DMODEL + c0 + tx];
  __syncthreads();
#pragma unroll
  for (int i = 0; i < 4; ++i)
    dst[(size_t)(c0 + ty + 8 * i) * DMODEL + r0 + tx] = f32_to_bf16(tile[tx][ty + 8 * i]);
}

__global__ void concat_bias_kernel(const float* __restrict__ bq, const float* __restrict__ bk,
                                   const float* __restrict__ bv, float* __restrict__ bqkv) {
  int i = blockIdx.x * 256 + threadIdx.x;
  float v = (i < 1024) ? bq[i] : (i < 2048) ? bk[i - 1024] : bv[i - 2048];
  bqkv[i] = v;
}

// ---------------- GEMM v3: dbuf + counted-vmcnt + bank-conflict swizzle ----------------
// R14 diagnosis: SQ_LDS_BANK_CONFLICT = 6.29M/dispatch = ~8 extra cyc per ds_read_b128.
// LDS rows are 64B (16 banks): a 16-lane read phase (col 0-15, fixed quad) hits only
// 2 four-bank groups (bank_grp = (col&1)*16 + quad*4) -> 8-way conflict (2.94x, m136).
// T2 fix (both-sides, rule #21): XOR the 16B-seg index with (row>>1)&3.
//   stage: fetch GLOBAL seg (ls ^ ((lr>>1)&3)); LDS write stays linear (async16 rule).
//   read: seg = quad ^ ((col>>1)&3) (row = wr*64+i*16+col => (row>>1)&3 = (col>>1)&3).
// Enumeration check: phase lanes now land 2 per group x 8 groups = 2-way = free.
template <int OUT_BF16, int FUSE_V>
__global__ __launch_bounds__(256) void gemm_bt_kernel(const u16* __restrict__ A,
                                                      const u16* __restrict__ Bt,
                                                      const float* __restrict__ bias,
                                                      void* __restrict__ Cout,
                                                      u16* __restrict__ vtout,
                                                      int M, int N, int K) {
  __shared__ u16 sA[2][128 * 32];
  __shared__ u16 sB[2][128 * 32];
  const int tid = threadIdx.x;
  const int wv = tid >> 6, lane = tid & 63;
  const int wr = wv >> 1, wc = wv & 1;
  const int col = lane & 15, quad = lane >> 4;
  const int m0 = blockIdx.x * 128;
  const int n0 = blockIdx.y * 128;

  f32x4 acc[4][4] = {};

  const int lr = tid >> 2;
  const int ls = (tid & 3) ^ ((lr >> 1) & 3); // swizzled global 16B-seg (T2 stage side)
  const size_t a_base = (size_t)(m0 + lr) * K + ls * 8;
  const size_t b_base = (size_t)(n0 + lr) * K + ls * 8;
  const int wvo = (tid >> 6) << 9; // per-wave 1KB chunk offset (u16 units)
  const int sseg = ((col >> 1) & 3); // read-side swizzle base

  // prologue: stage K-tile 0 into buffer 0 (4 loads, awaited at first loop-top wait)
  async16(A + a_base, sA[0] + wvo);
  async16(A + a_base + (size_t)64 * K, sA[0] + wvo + 2048);
  async16(Bt + b_base, sB[0] + wvo);
  async16(Bt + b_base + (size_t)64 * K, sB[0] + wvo + 2048);

  const int nit = K >> 5;
  for (int it = 0; it < nit; ++it) {
    const int cur = it & 1, nxt = cur ^ 1;

    if (it + 1 < nit) {
      const int k0 = (it + 1) << 5;
      async16(A + a_base + k0, sA[nxt] + wvo);
      async16(A + a_base + (size_t)64 * K + k0, sA[nxt] + wvo + 2048);
      async16(Bt + b_base + k0, sB[nxt] + wvo);
      async16(Bt + b_base + (size_t)64 * K + k0, sB[nxt] + wvo + 2048);
      asm volatile("s_waitcnt vmcnt(4)");
    } else {
      asm volatile("s_waitcnt vmcnt(0)");
    }
    __builtin_amdgcn_sched_barrier(0);
    __builtin_amdgcn_s_barrier(); // B1: K-tile it staged by ALL waves
    __builtin_amdgcn_sched_barrier(0);

    // read: LDS[row][s] holds global seg (s ^ ((row>>1)&3)); we want global seg quad
    // -> read LDS seg (quad ^ ((row>>1)&3)) = (quad ^ sseg) since row==col (mod 4 shifts)
    const int rseg = (quad ^ sseg) * 8;
    bf16x8 af[4], bfr[4];
#pragma unroll
    for (int i = 0; i < 4; ++i)
      af[i] = *(const bf16x8*)(sA[cur] + (wr * 64 + i * 16 + col) * 32 + rseg);
#pragma unroll
    for (int j = 0; j < 4; ++j)
      bfr[j] = *(const bf16x8*)(sB[cur] + (wc * 64 + j * 16 + col) * 32 + rseg);
#pragma unroll
    for (int i = 0; i < 4; ++i)
#pragma unroll
      for (int j = 0; j < 4; ++j)
        acc[i][j] = __builtin_amdgcn_mfma_f32_16x16x32_bf16(af[i], bfr[j], acc[i][j], 0, 0, 0);

    __builtin_amdgcn_sched_barrier(0);
    __builtin_amdgcn_s_barrier(); // B2: all waves done reading cur (no vmcnt drain)
    __builtin_amdgcn_sched_barrier(0);
  }

#pragma unroll
  for (int i = 0; i < 4; ++i) {
#pragma unroll
    for (int j = 0; j < 4; ++j) {
      int n = n0 + wc * 64 + j * 16 + col;
      float bia = bias[n];
      if (FUSE_V && n >= 2 * DMODEL) {
        // V column -> vt[((b*16+h)*64+dh)][s], 4 consecutive s packed into one 8B store
        const int hh = (n - 2 * DMODEL) >> 6, dh = n & 63;
        const int mb = m0 + wr * 64 + i * 16 + quad * 4;
        const int bb = mb >> 11, s0 = mb & 2047;
        uint2 pk;
        pk.x = pack_bf16x2(acc[i][j][0] + bia, acc[i][j][1] + bia);
        pk.y = pack_bf16x2(acc[i][j][2] + bia, acc[i][j][3] + bia);
        *(uint2*)(vtout + ((size_t)((bb * 16 + hh) * 64 + dh)) * SLEN + s0) = pk;
      } else {
        const int cstride = FUSE_V ? (2 * DMODEL) : N;
#pragma unroll
        for (int r = 0; r < 4; ++r) {
          int m = m0 + wr * 64 + i * 16 + quad * 4 + r;
          float v = acc[i][j][r] + bia;
          if (OUT_BF16)
            ((u16*)Cout)[(size_t)m * cstride + n] = f32_to_bf16(v);
          else
            ((float*)Cout)[(size_t)m * cstride + n] = v;
        }
      }
    }
  }
}

// ---------------- flash attention v18: grid (16,64), no register cap (R14 best, unchanged) ----------------
__global__ __launch_bounds__(256, 2) void attn_kernel(const u16* __restrict__ qk,
                                                      const u16* __restrict__ vt,
                                                      u16* __restrict__ out) {
  const int lid = blockIdx.y * 16 + blockIdx.x; // [0,1024)
  const int xcd = lid & 7;
  const int local = lid >> 3;            // [0,128)
  const int bh = xcd * 8 + (local & 7);  // same-bh blocks share XCD
  const int bx = 15 - (local >> 3);      // 0..15, heavy blocks (large bx) launch early
  const int b = bh >> 4, h = bh & 15;
  const int tid = threadIdx.x;
  const int wv = tid >> 6, lane = tid & 63;
  const int c = lane & 31, hi = lane >> 5;
  const int s = bx * 4 + wv; // strip id 0..63 (32 q-rows each)

  __shared__ u16 sK[2][64 * 64];
  __shared__ u16 sV[2][64 * 64];

  const u16* kbase = qk + ((size_t)(b * SLEN)) * (2 * DMODEL) + DMODEL + h * DHEAD;
  const u16* vbase = vt + ((size_t)bh * DHEAD) * SLEN;
  const float scl2 = 0.125f * 1.44269504088896f; // 1/sqrt(dh) * log2(e)

  // staging mapping: wave wv stages rows [wv*16, wv*16+16) of both tiles (2 calls each).
  // LDS[row][seg sgm] holds global seg (sgm ^ (row&7)).
  const int lrow = lane >> 3;
  const int sga = (lane & 7) ^ lrow;
  const int r0a = wv * 16, r0b = wv * 16 + 8;
  const int cs = c & 7;

  const int qbase = s * 32;
  const int nt_own = s / 2 + 1;
  const int nt = 2 * bx + 2; // block-uniform staging sweep (= max nt_own in block)

  // Q fragments (B operand): lane (c,hi) holds Q[qbase+c][ks*16 + hi*8 + e]
  const u16* qrow =
      qk + ((size_t)(b * SLEN + qbase + c)) * (2 * DMODEL) + h * DHEAD + hi * 8;
  bf16x8 aQ[4];
#pragma unroll
  for (int ks = 0; ks < 4; ++ks) aQ[ks] = *(const bf16x8*)(qrow + ks * 16);

  f32x16 accO[2] = {}; // [mdh]: O^T, col=q=c, row=dh=mdh*32+(r&3)+8*(r>>2)+4*hi
  float m2 = -1e30f, l_i = 0.0f;

  // prologue: stage tile 0 into buffer 0 (awaited at first loop-top wait)
  async16(kbase + (size_t)(r0a + lrow) * (2 * DMODEL) + sga * 8, sK[0] + r0a * 64);
  async16(kbase + (size_t)(r0b + lrow) * (2 * DMODEL) + sga * 8, sK[0] + r0b * 64);
  async16(vbase + (size_t)(r0a + lrow) * SLEN + sga * 8, sV[0] + r0a * 64);
  async16(vbase + (size_t)(r0b + lrow) * SLEN + sga * 8, sV[0] + r0b * 64);

  for (int t = 0; t < nt; ++t) {
    const int kv0 = t * 64;
    const int cur = t & 1, nxt = cur ^ 1;

    // issue prefetch of tile t+1, then wait only for tile t's 4 loads
    if (t + 1 < nt) {
      const int kvn = kv0 + 64;
      async16(kbase + (size_t)(kvn + r0a + lrow) * (2 * DMODEL) + sga * 8, sK[nxt] + r0a * 64);
      async16(kbase + (size_t)(kvn + r0b + lrow) * (2 * DMODEL) + sga * 8, sK[nxt] + r0b * 64);
      async16(vbase + (size_t)(r0a + lrow) * SLEN + kvn + sga * 8, sV[nxt] + r0a * 64);
      async16(vbase + (size_t)(r0b + lrow) * SLEN + kvn + sga * 8, sV[nxt] + r0b * 64);
      asm volatile("s_waitcnt vmcnt(4)");
    } else {
      asm volatile("s_waitcnt vmcnt(0)");
    }
    __builtin_amdgcn_sched_barrier(0);
    __builtin_amdgcn_s_barrier(); // B1: tile t staged by ALL waves
    __builtin_amdgcn_sched_barrier(0);

    if (t < nt_own) {
      const u16* sKc = sK[cur];
      const u16* sVc = sV[cur];
      // bK: K[kv=m*32+c][dh=ks*16+hi*8..+8) as one b128.
      // bV (sigma-mapped): element e holds V^T[dh=m*32+c][kv0+ks*16+4hi+(e&3)+8*(e>>2)]
      //   = two b64 chunks at +4*hi inside segs 2ks and 2ks+1.
      bf16x8 bK[2][4], bV[2][4];
#pragma unroll
      for (int m = 0; m < 2; ++m) {
        const int rb = (m * 32 + c) * 64;
#pragma unroll
        for (int ks = 0; ks < 4; ++ks) {
          bK[m][ks] = *(const bf16x8*)(sKc + rb + (((ks * 2 + hi) ^ cs) << 3));
          bf16x4 vlo = *(const bf16x4*)(sVc + rb + (((ks * 2) ^ cs) << 3) + 4 * hi);
          bf16x4 vhi = *(const bf16x4*)(sVc + rb + (((ks * 2 + 1) ^ cs) << 3) + 4 * hi);
          bV[m][ks] = __builtin_shufflevector(vlo, vhi, 0, 1, 2, 3, 4, 5, 6, 7);
        }
      }

      // S^T = K Q^T : accST[m] col=q=c, row=kv=m*32+(r&3)+8*(r>>2)+4*hi (raw)
      f32x16 accST[2] = {};
      __builtin_amdgcn_s_setprio(1);
#pragma unroll
      for (int ks = 0; ks < 4; ++ks)
#pragma unroll
        for (int m = 0; m < 2; ++m)
          accST[m] = __builtin_amdgcn_mfma_f32_32x32x16_bf16(bK[m][ks], aQ[ks],
                                                             accST[m], 0, 0, 0);
      __builtin_amdgcn_s_setprio(0);

      // causal mask on diagonal tile
      if (t == nt_own - 1) {
        const int q = qbase + c;
        const int kvh = kv0 + 4 * hi;
#pragma unroll
        for (int m = 0; m < 2; ++m)
#pragma unroll
          for (int r = 0; r < 16; ++r) {
            int kv = kvh + m * 32 + ((r & 3) + 8 * (r >> 2));
            if (kv > q) accST[m][r] = -1e30f;
          }
      }

      // online softmax (exp2 domain); full-row reduce = own 32 + partner via shfl^32
      float h0 = fmaxf(fmaxf(accST[0][0], accST[0][1]), fmaxf(accST[0][2], accST[0][3]));
      float h1 = fmaxf(fmaxf(accST[0][4], accST[0][5]), fmaxf(accST[0][6], accST[0][7]));
      float h2 = fmaxf(fmaxf(accST[0][8], accST[0][9]), fmaxf(accST[0][10], accST[0][11]));
      float h3 = fmaxf(fmaxf(accST[0][12], accST[0][13]), fmaxf(accST[0][14], accST[0][15]));
      float h4 = fmaxf(fmaxf(accST[1][0], accST[1][1]), fmaxf(accST[1][2], accST[1][3]));
      float h5 = fmaxf(fmaxf(accST[1][4], accST[1][5]), fmaxf(accST[1][6], accST[1][7]));
      float h6 = fmaxf(fmaxf(accST[1][8], accST[1][9]), fmaxf(accST[1][10], accST[1][11]));
      float h7 = fmaxf(fmaxf(accST[1][12], accST[1][13]), fmaxf(accST[1][14], accST[1][15]));
      float rmax = fmaxf(fmaxf(fmaxf(h0, h1), fmaxf(h2, h3)),
                         fmaxf(fmaxf(h4, h5), fmaxf(h6, h7)));
      rmax = fmaxf(rmax, __shfl_xor(rmax, 32));
      float rmaxs = rmax * scl2;
      const bool noresc = __all(rmaxs <= m2);
      float mnew = noresc ? m2 : fmaxf(m2, rmaxs);
      float alpha = noresc ? 1.0f : EXP2(m2 - mnew);
      m2 = mnew;

      float s0 = 0.f, s1 = 0.f, s2s = 0.f, s3 = 0.f;
#pragma unroll
      for (int m = 0; m < 2; ++m) {
#pragma unroll
        for (int r = 0; r < 16; r += 4) {
          float p0 = EXP2(__builtin_fmaf(accST[m][r + 0], scl2, -mnew));
          float p1 = EXP2(__builtin_fmaf(accST[m][r + 1], scl2, -mnew));
          float p2 = EXP2(__builtin_fmaf(accST[m][r + 2], scl2, -mnew));
          float p3 = EXP2(__builtin_fmaf(accST[m][r + 3], scl2, -mnew));
          accST[m][r + 0] = p0;
          accST[m][r + 1] = p1;
          accST[m][r + 2] = p2;
          accST[m][r + 3] = p3;
          s0 += p0;
          s1 += p1;
          s2s += p2;
          s3 += p3;
        }
      }
      float sacc = (s0 + s1) + (s2s + s3);
      sacc += __shfl_xor(sacc, 32);
      if (noresc) {
        l_i += sacc;
      } else {
        l_i = l_i * alpha + sacc;
#pragma unroll
        for (int m = 0; m < 2; ++m)
#pragma unroll
          for (int r = 0; r < 16; ++r) accO[m][r] *= alpha;
      }

      // P -> B-fragments, sigma-mapped: each lane packs its OWN rows in natural order.
      // aP[2m+s'] element e = P[(2m+s')*16 + 4hi + (e&3) + 8*(e>>2)][q=c] = accST[m][8s'+e].
      bf16x8 aP[4];
#pragma unroll
      for (int m = 0; m < 2; ++m)
#pragma unroll
        for (int sp = 0; sp < 2; ++sp) {
          union {
            uint4 u;
            bf16x8 v;
          } cvt;
          cvt.u.x = pack_trunc(accST[m][8 * sp + 0], accST[m][8 * sp + 1]);
          cvt.u.y = pack_trunc(accST[m][8 * sp + 2], accST[m][8 * sp + 3]);
          cvt.u.z = pack_trunc(accST[m][8 * sp + 4], accST[m][8 * sp + 5]);
          cvt.u.w = pack_trunc(accST[m][8 * sp + 6], accST[m][8 * sp + 7]);
          aP[m * 2 + sp] = cvt.v;
        }

      // O^T += V^T P^T (A and B share the sigma k-permutation per 16-slice)
      __builtin_amdgcn_s_setprio(1);
#pragma unroll
      for (int ks = 0; ks < 4; ++ks)
#pragma unroll
        for (int m = 0; m < 2; ++m)
          accO[m] = __builtin_amdgcn_mfma_f32_32x32x16_bf16(bV[m][ks], aP[ks],
                                                            accO[m], 0, 0, 0);
      __builtin_amdgcn_s_setprio(0);
    }

    __builtin_amdgcn_sched_barrier(0);
    __builtin_amdgcn_s_barrier(); // B2: all waves done reading cur (no vmcnt drain)
    __builtin_amdgcn_sched_barrier(0);
  }

  // epilogue: O^T col=q row=dh -> out[q][dh], packed dwordx2 stores
  {
    float rl = 1.0f / l_i;
    size_t rowoff =
        ((size_t)(b * SLEN + qbase + c)) * DMODEL + h * DHEAD + 4 * hi;
#pragma unroll
    for (int m = 0; m < 2; ++m)
#pragma unroll
      for (int j = 0; j < 4; ++j) {
        uint2 pk;
        pk.x = pack_round(accO[m][4 * j + 0] * rl, accO[m][4 * j + 1] * rl);
        pk.y = pack_round(accO[m][4 * j + 2] * rl, accO[m][4 * j + 3] * rl);
        *(uint2*)(out + rowoff + m * 32 + 8 * j) = pk;
      }
  }
}

// ---------------- launch ----------------

extern "C" void kernel_launch(void* const* d_in, const int* in_sizes, int n_in,
                              void* d_out, int out_size, void* d_ws, size_t ws_size,
                              hipStream_t stream) {
  const float* x = (const float*)d_in[0];
  const float* Wq = (const float*)d_in[1];
  const float* bq = (const float*)d_in[2];
  const float* Wk = (const float*)d_in[3];
  const float* bk = (const float*)d_in[4];
  const float* Wv = (const float*)d_in[5];
  const float* bv = (const float*)d_in[6];
  const float* Wo = (const float*)d_in[7];
  const float* bo = (const float*)d_in[8];

  char* ws = (char*)d_ws;
  u16* xb = (u16*)ws;                              // 16 MB
  u16* wqkvt = (u16*)(ws + ((size_t)16 << 20));    // 6 MB
  u16* wot = (u16*)(ws + ((size_t)22 << 20));      // 2 MB
  u16* qk = (u16*)(ws + ((size_t)24 << 20));       // 32 MB (Q|K, row stride 2048)
  u16* vtp = (u16*)(ws + ((size_t)56 << 20));      // 16 MB (V transposed, fused write)
  u16* attnO = (u16*)(ws + ((size_t)72 << 20));    // 16 MB
  float* bqkv = (float*)(ws + ((size_t)88 << 20)); // 12 KB

  convert_x_kernel<<<4096, 256, 0, stream>>>(x, xb);
  transpose_w_kernel<<<dim3(32, 32, 4), 256, 0, stream>>>(Wq, Wk, Wv, Wo, wqkvt, wot);
  concat_bias_kernel<<<12, 256, 0, stream>>>(bq, bk, bv, bqkv);
  gemm_bt_kernel<1, 1><<<dim3(64, 24), 256, 0, stream>>>(xb, wqkvt, bqkv, (void*)qk, vtp,
                                                         MROWS, 3 * DMODEL, DMODEL);
  attn_kernel<<<dim3(16, 64), 256, 0, stream>>>(qk, vtp, attnO);
  gemm_bt_kernel<0, 0><<<dim3(64, 8), 256, 0, stream>>>(attnO, wot, bo, d_out, nullptr,
                                                        MROWS, DMODEL, DMODEL);
}

// Round 16
// 251.554 us; speedup vs baseline: 1.3952x; 1.0287x over previous
//
#include <hip/hip_runtime.h>

typedef unsigned short u16;
typedef unsigned int u32;
typedef __bf16 bf16x4 __attribute__((ext_vector_type(4)));
typedef __bf16 bf16x8 __attribute__((ext_vector_type(8)));
typedef float f32x4 __attribute__((ext_vector_type(4)));
typedef float f32x16 __attribute__((ext_vector_type(16)));

#define BATCH 4
#define SLEN 2048
#define DMODEL 1024
#define NHEAD 16
#define DHEAD 64
#define MROWS (BATCH * SLEN) /* 8192 */

__device__ __forceinline__ u16 f32_to_bf16(float f) {
  u32 u = __float_as_uint(f);
  u32 r = (u + 0x7FFFu + ((u >> 16) & 1u)) >> 16;
  return (u16)r;
}
__device__ __forceinline__ u32 pack_bf16x2(float a, float b) {
  return (u32)f32_to_bf16(a) | ((u32)f32_to_bf16(b) << 16);
}

// pack two f32 -> two bf16 (truncate), 1 v_perm_b32
__device__ __forceinline__ u32 pack_trunc(float lo, float hi) {
#if __has_builtin(__builtin_amdgcn_perm)
  return __builtin_amdgcn_perm(__float_as_uint(hi), __float_as_uint(lo), 0x07060302u);
#else
  return (__float_as_uint(hi) & 0xFFFF0000u) | (__float_as_uint(lo) >> 16);
#endif
}
// pack with round-half-up (epilogue)
__device__ __forceinline__ u32 pack_round(float lo, float hi) {
  u32 ul = __float_as_uint(lo) + 0x8000u;
  u32 uh = __float_as_uint(hi) + 0x8000u;
#if __has_builtin(__builtin_amdgcn_perm)
  return __builtin_amdgcn_perm(uh, ul, 0x07060302u);
#else
  return (uh & 0xFFFF0000u) | (ul >> 16);
#endif
}

#if __has_builtin(__builtin_amdgcn_exp2f)
#define EXP2(x) __builtin_amdgcn_exp2f(x)
#else
#define EXP2(x) exp2f(x)
#endif

// async global->LDS, 16 B per lane; lds dest = wave-uniform base + lane*16
typedef const __attribute__((address_space(1))) void* gas_cv;
typedef __attribute__((address_space(3))) void* las_v;
__device__ __forceinline__ void async16(const u16* g, u16* l) {
  __builtin_amdgcn_global_load_lds((gas_cv)g, (las_v)l, 16, 0, 0);
}

// ---------------- fused prep kernel ----------------
// R15 finding: summed kernel durations leave a ~75us gap vs total -> ~10us/launch
// dispatch overhead across 6 kernels. Fuse the 3 independent prep kernels into ONE
// (block-uniform branch on blockIdx.x range); bodies byte-identical to the originals.
//   [0,4096)      : convert_x  (x f32 -> xb bf16, 8 elems/thread)
//   [4096,8192)   : transpose_w (z = idx>>10, 32x32 tile transpose + bf16)
//   [8192,8204)   : concat_bias (bq|bk|bv -> bqkv f32)
__global__ void prep_kernel(const float* __restrict__ x, const float* __restrict__ Wq,
                            const float* __restrict__ Wk, const float* __restrict__ Wv,
                            const float* __restrict__ Wo, const float* __restrict__ bq,
                            const float* __restrict__ bk, const float* __restrict__ bv,
                            u16* __restrict__ xb, u16* __restrict__ wqkvt,
                            u16* __restrict__ wot, float* __restrict__ bqkv) {
  const int bid = blockIdx.x;
  if (bid < 4096) {
    size_t i = ((size_t)bid * 256 + threadIdx.x) * 8;
    float4 v0 = *(const float4*)(x + i);
    float4 v1 = *(const float4*)(x + i + 4);
    uint4 o;
    o.x = pack_bf16x2(v0.x, v0.y);
    o.y = pack_bf16x2(v0.z, v0.w);
    o.z = pack_bf16x2(v1.x, v1.y);
    o.w = pack_bf16x2(v1.z, v1.w);
    *(uint4*)(xb + i) = o;
  } else if (bid < 8192) {
    __shared__ float tile[32][33];
    const int idx = bid - 4096;
    const int z = idx >> 10;
    const int rem = idx & 1023;
    const float* src = (z == 0) ? Wq : (z == 1) ? Wk : (z == 2) ? Wv : Wo;
    u16* dst = (z < 3) ? (wqkvt + (size_t)z * DMODEL * DMODEL) : wot;
    const int c0 = (rem & 31) * 32, r0 = (rem >> 5) * 32;
    const int tx = threadIdx.x & 31, ty = threadIdx.x >> 5;
#pragma unroll
    for (int i = 0; i < 4; ++i)
      tile[ty + 8 * i][tx] = src[(size_t)(r0 + ty + 8 * i) * DMODEL + c0 + tx];
    __syncthreads();
#pragma unroll
    for (int i = 0; i < 4; ++i)
      dst[(size_t)(c0 + ty + 8 * i) * DMODEL + r0 + tx] = f32_to_bf16(tile[tx][ty + 8 * i]);
  } else {
    const int i = (bid - 8192) * 256 + threadIdx.x;
    float v = (i < 1024) ? bq[i] : (i < 2048) ? bk[i - 1024] : bv[i - 2048];
    bqkv[i] = v;
  }
}

// ---------------- GEMM v3: dbuf + counted-vmcnt + bank-conflict swizzle (R15, unchanged) ----------------
template <int OUT_BF16, int FUSE_V>
__global__ __launch_bounds__(256) void gemm_bt_kernel(const u16* __restrict__ A,
                                                      const u16* __restrict__ Bt,
                                                      const float* __restrict__ bias,
                                                      void* __restrict__ Cout,
                                                      u16* __restrict__ vtout,
                                                      int M, int N, int K) {
  __shared__ u16 sA[2][128 * 32];
  __shared__ u16 sB[2][128 * 32];
  const int tid = threadIdx.x;
  const int wv = tid >> 6, lane = tid & 63;
  const int wr = wv >> 1, wc = wv & 1;
  const int col = lane & 15, quad = lane >> 4;
  const int m0 = blockIdx.x * 128;
  const int n0 = blockIdx.y * 128;

  f32x4 acc[4][4] = {};

  const int lr = tid >> 2;
  const int ls = (tid & 3) ^ ((lr >> 1) & 3); // swizzled global 16B-seg (T2 stage side)
  const size_t a_base = (size_t)(m0 + lr) * K + ls * 8;
  const size_t b_base = (size_t)(n0 + lr) * K + ls * 8;
  const int wvo = (tid >> 6) << 9; // per-wave 1KB chunk offset (u16 units)
  const int sseg = ((col >> 1) & 3); // read-side swizzle base

  // prologue: stage K-tile 0 into buffer 0 (4 loads, awaited at first loop-top wait)
  async16(A + a_base, sA[0] + wvo);
  async16(A + a_base + (size_t)64 * K, sA[0] + wvo + 2048);
  async16(Bt + b_base, sB[0] + wvo);
  async16(Bt + b_base + (size_t)64 * K, sB[0] + wvo + 2048);

  const int nit = K >> 5;
  for (int it = 0; it < nit; ++it) {
    const int cur = it & 1, nxt = cur ^ 1;

    if (it + 1 < nit) {
      const int k0 = (it + 1) << 5;
      async16(A + a_base + k0, sA[nxt] + wvo);
      async16(A + a_base + (size_t)64 * K + k0, sA[nxt] + wvo + 2048);
      async16(Bt + b_base + k0, sB[nxt] + wvo);
      async16(Bt + b_base + (size_t)64 * K + k0, sB[nxt] + wvo + 2048);
      asm volatile("s_waitcnt vmcnt(4)");
    } else {
      asm volatile("s_waitcnt vmcnt(0)");
    }
    __builtin_amdgcn_sched_barrier(0);
    __builtin_amdgcn_s_barrier(); // B1: K-tile it staged by ALL waves
    __builtin_amdgcn_sched_barrier(0);

    // read: LDS[row][s] holds global seg (s ^ ((row>>1)&3)); want global seg quad
    const int rseg = (quad ^ sseg) * 8;
    bf16x8 af[4], bfr[4];
#pragma unroll
    for (int i = 0; i < 4; ++i)
      af[i] = *(const bf16x8*)(sA[cur] + (wr * 64 + i * 16 + col) * 32 + rseg);
#pragma unroll
    for (int j = 0; j < 4; ++j)
      bfr[j] = *(const bf16x8*)(sB[cur] + (wc * 64 + j * 16 + col) * 32 + rseg);
#pragma unroll
    for (int i = 0; i < 4; ++i)
#pragma unroll
      for (int j = 0; j < 4; ++j)
        acc[i][j] = __builtin_amdgcn_mfma_f32_16x16x32_bf16(af[i], bfr[j], acc[i][j], 0, 0, 0);

    __builtin_amdgcn_sched_barrier(0);
    __builtin_amdgcn_s_barrier(); // B2: all waves done reading cur (no vmcnt drain)
    __builtin_amdgcn_sched_barrier(0);
  }

#pragma unroll
  for (int i = 0; i < 4; ++i) {
#pragma unroll
    for (int j = 0; j < 4; ++j) {
      int n = n0 + wc * 64 + j * 16 + col;
      float bia = bias[n];
      if (FUSE_V && n >= 2 * DMODEL) {
        // V column -> vt[((b*16+h)*64+dh)][s], 4 consecutive s packed into one 8B store
        const int hh = (n - 2 * DMODEL) >> 6, dh = n & 63;
        const int mb = m0 + wr * 64 + i * 16 + quad * 4;
        const int bb = mb >> 11, s0 = mb & 2047;
        uint2 pk;
        pk.x = pack_bf16x2(acc[i][j][0] + bia, acc[i][j][1] + bia);
        pk.y = pack_bf16x2(acc[i][j][2] + bia, acc[i][j][3] + bia);
        *(uint2*)(vtout + ((size_t)((bb * 16 + hh) * 64 + dh)) * SLEN + s0) = pk;
      } else {
        const int cstride = FUSE_V ? (2 * DMODEL) : N;
#pragma unroll
        for (int r = 0; r < 4; ++r) {
          int m = m0 + wr * 64 + i * 16 + quad * 4 + r;
          float v = acc[i][j][r] + bia;
          if (OUT_BF16)
            ((u16*)Cout)[(size_t)m * cstride + n] = f32_to_bf16(v);
          else
            ((float*)Cout)[(size_t)m * cstride + n] = v;
        }
      }
    }
  }
}

// ---------------- flash attention v18: grid (16,64), no register cap (R14 best, unchanged) ----------------
__global__ __launch_bounds__(256, 2) void attn_kernel(const u16* __restrict__ qk,
                                                      const u16* __restrict__ vt,
                                                      u16* __restrict__ out) {
  const int lid = blockIdx.y * 16 + blockIdx.x; // [0,1024)
  const int xcd = lid & 7;
  const int local = lid >> 3;            // [0,128)
  const int bh = xcd * 8 + (local & 7);  // same-bh blocks share XCD
  const int bx = 15 - (local >> 3);      // 0..15, heavy blocks (large bx) launch early
  const int b = bh >> 4, h = bh & 15;
  const int tid = threadIdx.x;
  const int wv = tid >> 6, lane = tid & 63;
  const int c = lane & 31, hi = lane >> 5;
  const int s = bx * 4 + wv; // strip id 0..63 (32 q-rows each)

  __shared__ u16 sK[2][64 * 64];
  __shared__ u16 sV[2][64 * 64];

  const u16* kbase = qk + ((size_t)(b * SLEN)) * (2 * DMODEL) + DMODEL + h * DHEAD;
  const u16* vbase = vt + ((size_t)bh * DHEAD) * SLEN;
  const float scl2 = 0.125f * 1.44269504088896f; // 1/sqrt(dh) * log2(e)

  // staging mapping: wave wv stages rows [wv*16, wv*16+16) of both tiles (2 calls each).
  // LDS[row][seg sgm] holds global seg (sgm ^ (row&7)).
  const int lrow = lane >> 3;
  const int sga = (lane & 7) ^ lrow;
  const int r0a = wv * 16, r0b = wv * 16 + 8;
  const int cs = c & 7;

  const int qbase = s * 32;
  const int nt_own = s / 2 + 1;
  const int nt = 2 * bx + 2; // block-uniform staging sweep (= max nt_own in block)

  // Q fragments (B operand): lane (c,hi) holds Q[qbase+c][ks*16 + hi*8 + e]
  const u16* qrow =
      qk + ((size_t)(b * SLEN + qbase + c)) * (2 * DMODEL) + h * DHEAD + hi * 8;
  bf16x8 aQ[4];
#pragma unroll
  for (int ks = 0; ks < 4; ++ks) aQ[ks] = *(const bf16x8*)(qrow + ks * 16);

  f32x16 accO[2] = {}; // [mdh]: O^T, col=q=c, row=dh=mdh*32+(r&3)+8*(r>>2)+4*hi
  float m2 = -1e30f, l_i = 0.0f;

  // prologue: stage tile 0 into buffer 0 (awaited at first loop-top wait)
  async16(kbase + (size_t)(r0a + lrow) * (2 * DMODEL) + sga * 8, sK[0] + r0a * 64);
  async16(kbase + (size_t)(r0b + lrow) * (2 * DMODEL) + sga * 8, sK[0] + r0b * 64);
  async16(vbase + (size_t)(r0a + lrow) * SLEN + sga * 8, sV[0] + r0a * 64);
  async16(vbase + (size_t)(r0b + lrow) * SLEN + sga * 8, sV[0] + r0b * 64);

  for (int t = 0; t < nt; ++t) {
    const int kv0 = t * 64;
    const int cur = t & 1, nxt = cur ^ 1;

    // issue prefetch of tile t+1, then wait only for tile t's 4 loads
    if (t + 1 < nt) {
      const int kvn = kv0 + 64;
      async16(kbase + (size_t)(kvn + r0a + lrow) * (2 * DMODEL) + sga * 8, sK[nxt] + r0a * 64);
      async16(kbase + (size_t)(kvn + r0b + lrow) * (2 * DMODEL) + sga * 8, sK[nxt] + r0b * 64);
      async16(vbase + (size_t)(r0a + lrow) * SLEN + kvn + sga * 8, sV[nxt] + r0a * 64);
      async16(vbase + (size_t)(r0b + lrow) * SLEN + kvn + sga * 8, sV[nxt] + r0b * 64);
      asm volatile("s_waitcnt vmcnt(4)");
    } else {
      asm volatile("s_waitcnt vmcnt(0)");
    }
    __builtin_amdgcn_sched_barrier(0);
    __builtin_amdgcn_s_barrier(); // B1: tile t staged by ALL waves
    __builtin_amdgcn_sched_barrier(0);

    if (t < nt_own) {
      const u16* sKc = sK[cur];
      const u16* sVc = sV[cur];
      // bK: K[kv=m*32+c][dh=ks*16+hi*8..+8) as one b128.
      // bV (sigma-mapped): element e holds V^T[dh=m*32+c][kv0+ks*16+4hi+(e&3)+8*(e>>2)]
      //   = two b64 chunks at +4*hi inside segs 2ks and 2ks+1.
      bf16x8 bK[2][4], bV[2][4];
#pragma unroll
      for (int m = 0; m < 2; ++m) {
        const int rb = (m * 32 + c) * 64;
#pragma unroll
        for (int ks = 0; ks < 4; ++ks) {
          bK[m][ks] = *(const bf16x8*)(sKc + rb + (((ks * 2 + hi) ^ cs) << 3));
          bf16x4 vlo = *(const bf16x4*)(sVc + rb + (((ks * 2) ^ cs) << 3) + 4 * hi);
          bf16x4 vhi = *(const bf16x4*)(sVc + rb + (((ks * 2 + 1) ^ cs) << 3) + 4 * hi);
          bV[m][ks] = __builtin_shufflevector(vlo, vhi, 0, 1, 2, 3, 4, 5, 6, 7);
        }
      }

      // S^T = K Q^T : accST[m] col=q=c, row=kv=m*32+(r&3)+8*(r>>2)+4*hi (raw)
      f32x16 accST[2] = {};
      __builtin_amdgcn_s_setprio(1);
#pragma unroll
      for (int ks = 0; ks < 4; ++ks)
#pragma unroll
        for (int m = 0; m < 2; ++m)
          accST[m] = __builtin_amdgcn_mfma_f32_32x32x16_bf16(bK[m][ks], aQ[ks],
                                                             accST[m], 0, 0, 0);
      __builtin_amdgcn_s_setprio(0);

      // causal mask on diagonal tile
      if (t == nt_own - 1) {
        const int q = qbase + c;
        const int kvh = kv0 + 4 * hi;
#pragma unroll
        for (int m = 0; m < 2; ++m)
#pragma unroll
          for (int r = 0; r < 16; ++r) {
            int kv = kvh + m * 32 + ((r & 3) + 8 * (r >> 2));
            if (kv > q) accST[m][r] = -1e30f;
          }
      }

      // online softmax (exp2 domain); full-row reduce = own 32 + partner via shfl^32
      float h0 = fmaxf(fmaxf(accST[0][0], accST[0][1]), fmaxf(accST[0][2], accST[0][3]));
      float h1 = fmaxf(fmaxf(accST[0][4], accST[0][5]), fmaxf(accST[0][6], accST[0][7]));
      float h2 = fmaxf(fmaxf(accST[0][8], accST[0][9]), fmaxf(accST[0][10], accST[0][11]));
      float h3 = fmaxf(fmaxf(accST[0][12], accST[0][13]), fmaxf(accST[0][14], accST[0][15]));
      float h4 = fmaxf(fmaxf(accST[1][0], accST[1][1]), fmaxf(accST[1][2], accST[1][3]));
      float h5 = fmaxf(fmaxf(accST[1][4], accST[1][5]), fmaxf(accST[1][6], accST[1][7]));
      float h6 = fmaxf(fmaxf(accST[1][8], accST[1][9]), fmaxf(accST[1][10], accST[1][11]));
      float h7 = fmaxf(fmaxf(accST[1][12], accST[1][13]), fmaxf(accST[1][14], accST[1][15]));
      float rmax = fmaxf(fmaxf(fmaxf(h0, h1), fmaxf(h2, h3)),
                         fmaxf(fmaxf(h4, h5), fmaxf(h6, h7)));
      rmax = fmaxf(rmax, __shfl_xor(rmax, 32));
      float rmaxs = rmax * scl2;
      const bool noresc = __all(rmaxs <= m2);
      float mnew = noresc ? m2 : fmaxf(m2, rmaxs);
      float alpha = noresc ? 1.0f : EXP2(m2 - mnew);
      m2 = mnew;

      float s0 = 0.f, s1 = 0.f, s2s = 0.f, s3 = 0.f;
#pragma unroll
      for (int m = 0; m < 2; ++m) {
#pragma unroll
        for (int r = 0; r < 16; r += 4) {
          float p0 = EXP2(__builtin_fmaf(accST[m][r + 0], scl2, -mnew));
          float p1 = EXP2(__builtin_fmaf(accST[m][r + 1], scl2, -mnew));
          float p2 = EXP2(__builtin_fmaf(accST[m][r + 2], scl2, -mnew));
          float p3 = EXP2(__builtin_fmaf(accST[m][r + 3], scl2, -mnew));
          accST[m][r + 0] = p0;
          accST[m][r + 1] = p1;
          accST[m][r + 2] = p2;
          accST[m][r + 3] = p3;
          s0 += p0;
          s1 += p1;
          s2s += p2;
          s3 += p3;
        }
      }
      float sacc = (s0 + s1) + (s2s + s3);
      sacc += __shfl_xor(sacc, 32);
      if (noresc) {
        l_i += sacc;
      } else {
        l_i = l_i * alpha + sacc;
#pragma unroll
        for (int m = 0; m < 2; ++m)
#pragma unroll
          for (int r = 0; r < 16; ++r) accO[m][r] *= alpha;
      }

      // P -> B-fragments, sigma-mapped: each lane packs its OWN rows in natural order.
      // aP[2m+s'] element e = P[(2m+s')*16 + 4hi + (e&3) + 8*(e>>2)][q=c] = accST[m][8s'+e].
      bf16x8 aP[4];
#pragma unroll
      for (int m = 0; m < 2; ++m)
#pragma unroll
        for (int sp = 0; sp < 2; ++sp) {
          union {
            uint4 u;
            bf16x8 v;
          } cvt;
          cvt.u.x = pack_trunc(accST[m][8 * sp + 0], accST[m][8 * sp + 1]);
          cvt.u.y = pack_trunc(accST[m][8 * sp + 2], accST[m][8 * sp + 3]);
          cvt.u.z = pack_trunc(accST[m][8 * sp + 4], accST[m][8 * sp + 5]);
          cvt.u.w = pack_trunc(accST[m][8 * sp + 6], accST[m][8 * sp + 7]);
          aP[m * 2 + sp] = cvt.v;
        }

      // O^T += V^T P^T (A and B share the sigma k-permutation per 16-slice)
      __builtin_amdgcn_s_setprio(1);
#pragma unroll
      for (int ks = 0; ks < 4; ++ks)
#pragma unroll
        for (int m = 0; m < 2; ++m)
          accO[m] = __builtin_amdgcn_mfma_f32_32x32x16_bf16(bV[m][ks], aP[ks],
                                                            accO[m], 0, 0, 0);
      __builtin_amdgcn_s_setprio(0);
    }

    __builtin_amdgcn_sched_barrier(0);
    __builtin_amdgcn_s_barrier(); // B2: all waves done reading cur (no vmcnt drain)
    __builtin_amdgcn_sched_barrier(0);
  }

  // epilogue: O^T col=q row=dh -> out[q][dh], packed dwordx2 stores
  {
    float rl = 1.0f / l_i;
    size_t rowoff =
        ((size_t)(b * SLEN + qbase + c)) * DMODEL + h * DHEAD + 4 * hi;
#pragma unroll
    for (int m = 0; m < 2; ++m)
#pragma unroll
      for (int j = 0; j < 4; ++j) {
        uint2 pk;
        pk.x = pack_round(accO[m][4 * j + 0] * rl, accO[m][4 * j + 1] * rl);
        pk.y = pack_round(accO[m][4 * j + 2] * rl, accO[m][4 * j + 3] * rl);
        *(uint2*)(out + rowoff + m * 32 + 8 * j) = pk;
      }
  }
}

// ---------------- launch ----------------

extern "C" void kernel_launch(void* const* d_in, const int* in_sizes, int n_in,
                              void* d_out, int out_size, void* d_ws, size_t ws_size,
                              hipStream_t stream) {
  const float* x = (const float*)d_in[0];
  const float* Wq = (const float*)d_in[1];
  const float* bq = (const float*)d_in[2];
  const float* Wk = (const float*)d_in[3];
  const float* bk = (const float*)d_in[4];
  const float* Wv = (const float*)d_in[5];
  const float* bv = (const float*)d_in[6];
  const float* Wo = (const float*)d_in[7];
  const float* bo = (const float*)d_in[8];

  char* ws = (char*)d_ws;
  u16* xb = (u16*)ws;                              // 16 MB
  u16* wqkvt = (u16*)(ws + ((size_t)16 << 20));    // 6 MB
  u16* wot = (u16*)(ws + ((size_t)22 << 20));      // 2 MB
  u16* qk = (u16*)(ws + ((size_t)24 << 20));       // 32 MB (Q|K, row stride 2048)
  u16* vtp = (u16*)(ws + ((size_t)56 << 20));      // 16 MB (V transposed, fused write)
  u16* attnO = (u16*)(ws + ((size_t)72 << 20));    // 16 MB
  float* bqkv = (float*)(ws + ((size_t)88 << 20)); // 12 KB

  prep_kernel<<<8204, 256, 0, stream>>>(x, Wq, Wk, Wv, Wo, bq, bk, bv,
                                        xb, wqkvt, wot, bqkv);
  gemm_bt_kernel<1, 1><<<dim3(64, 24), 256, 0, stream>>>(xb, wqkvt, bqkv, (void*)qk, vtp,
                                                         MROWS, 3 * DMODEL, DMODEL);
  attn_kernel<<<dim3(16, 64), 256, 0, stream>>>(qk, vtp, attnO);
  gemm_bt_kernel<0, 0><<<dim3(64, 8), 256, 0, stream>>>(attnO, wot, bo, d_out, nullptr,
                                                        MROWS, DMODEL, DMODEL);
}